// Round 19
// baseline (183.057 us; speedup 1.0000x reference)
//
#include <hip/hip_runtime.h>
#include <hip/hip_fp16.h>
#include <math.h>

#define SDIM 224
#define KTOP 10
#define NB 2
#define NV 5023
#define NF 5000
#define BLUR 1e-4f
#define IMG_SZ (NB * SDIM * SDIM)   // 100352
#define NW 8             // waves per block
#define SEG (NF / NW)    // 625
#define CAP 1024         // LDS survivor-list capacity
#define HT 0.031251f     // tile half-extent (7/224) + float slop
#define COV_THR 0.04422f // halfdiag(0.044194)+eps: certain whole-tile cover
#define REL_THR (-0.0543f) // -(halfdiag + 0.01 blur reach + eps)

// Exact (numpy-op-order) point-segment distance^2, matching _edge_d2.
__device__ __forceinline__ float seg_d2_exact(float ax, float ay, float abx, float aby,
                                              float L, float px, float py) {
    float apx = __fsub_rn(px, ax), apy = __fsub_rn(py, ay);
    float dot = __fadd_rn(__fmul_rn(apx, abx), __fmul_rn(apy, aby));
    float t = __fdiv_rn(dot, L);
    t = fminf(fmaxf(t, 0.0f), 1.0f);
    float prx = __fadd_rn(ax, __fmul_rn(t, abx));
    float pry = __fadd_rn(ay, __fmul_rn(t, aby));
    float dx = __fsub_rn(px, prx), dy = __fsub_rn(py, pry);
    return __fadd_rn(__fmul_rn(dx, dx), __fmul_rn(dy, dy));
}

// ga[f]    = {Zx, Zy, Zc, mgc}; hh[3f..] = {v0,v1},{v2,z0,z1},{z2,area} (bit-exact data);
// cc[3f..] = normalized edge lines + z bounds {.., zloF, zhiF, 0}  (conservative gates).
// ALL-FP32 preprocess (R16-proven): gate-only values, margins widened for fp32 error.
__global__ __launch_bounds__(64) void preprocess_kernel(const float* __restrict__ verts,
                                  const int* __restrict__ faces,
                                  float4* __restrict__ ga,
                                  float4* __restrict__ hh,
                                  float4* __restrict__ cc,
                                  float* __restrict__ out)
{
    const int idx = blockIdx.x * blockDim.x + threadIdx.x;
    if (idx < NB * NV) out[IMG_SZ + idx] = 0.0f;     // zero visibility region
    if (idx >= NB * NF) return;
    const int b = idx / NF;
    const int* fp = faces + (size_t)idx * 3;
    const int i0 = fp[0], i1 = fp[1], i2 = fp[2];
    const float* vb = verts + (size_t)b * NV * 3;
    const float v0x = -vb[i0*3+0], v0y = -vb[i0*3+1], z0 = vb[i0*3+2];
    const float v1x = -vb[i1*3+0], v1y = -vb[i1*3+1], z1 = vb[i1*3+2];
    const float v2x = -vb[i2*3+0], v2y = -vb[i2*3+1], z2 = vb[i2*3+2];
    const float e01x = __fsub_rn(v1x, v0x), e01y = __fsub_rn(v1y, v0y);
    const float e12x = __fsub_rn(v2x, v1x), e12y = __fsub_rn(v2y, v1y);
    const float e20x = __fsub_rn(v0x, v2x), e20y = __fsub_rn(v0y, v2y);
    const float area = __fsub_rn(__fmul_rn(e01x, __fsub_rn(v2y, v0y)),
                                 __fmul_rn(e01y, __fsub_rn(v2x, v0x)));
    const bool good = fabsf(area) > 1e-10f;
    const float area_safe = good ? area : 1.0f;

    float Zx = 0.0f, Zy = 0.0f, Zc = 0.0f;
    float mgc = -1.0f;   // mgc<0 => zt window always fails
    float n0x=0,n0y=0,n0c=-3e38f, n1x=0,n1y=0,n1c=-3e38f, n2x=0,n2y=0,n2c=-3e38f;
    float zloF = 3e38f, zhiF = -1.0f;
    if (good) {
        const float invA = 1.0f / area;
        const float c0c = e12y*v1x - e12x*v1y;
        const float c1c = e20y*v2x - e20x*v2y;
        const float c2c = e01y*v0x - e01x*v0y;
        Zx = (-e12y*z0 - e20y*z1 - e01y*z2) * invA;
        Zy = ( e12x*z0 + e20x*z1 + e01x*z2) * invA;
        Zc = (c0c*z0 + c1c*z1 + c2c*z2) * invA;
        const float B0 = fabsf(e12x)*(1.0f+fabsf(v1y)) + fabsf(e12y)*(1.0f+fabsf(v1x));
        const float B1 = fabsf(e20x)*(1.0f+fabsf(v2y)) + fabsf(e20y)*(1.0f+fabsf(v2x));
        const float B2 = fabsf(e01x)*(1.0f+fabsf(v0y)) + fabsf(e01y)*(1.0f+fabsf(v0x));
        const float B = (B0*z0 + B1*z1 + B2*z2) * fabsf(invA);
        mgc = 8e-6f * B + 1e-7f;   // >=4x headroom over worst-case fp32 error
        const float s = (area > 0.0f) ? 1.0f : -1.0f;
        const float l12 = sqrtf(e12x*e12x + e12y*e12y);
        const float l20 = sqrtf(e20x*e20x + e20y*e20y);
        const float l01 = sqrtf(e01x*e01x + e01y*e01y);
        const float i12 = s / fmaxf(l12, 1e-30f);
        const float i20 = s / fmaxf(l20, 1e-30f);
        const float i01 = s / fmaxf(l01, 1e-30f);
        n0x = -e12y * i12;
        n0y =  e12x * i12;
        n0c = (e12y*v1x - e12x*v1y) * i12;
        n1x = -e20y * i20;
        n1y =  e20x * i20;
        n1c = (e20y*v2x - e20x*v2y) * i20;
        n2x = -e01y * i01;
        n2y =  e01x * i01;
        n2c = (e01y*v0x - e01x*v0y) * i01;
        const float gradZ = sqrtf(Zx*Zx + Zy*Zy);
        const float zminV = fminf(z0, fminf(z1, z2));
        const float zmaxV = fmaxf(z0, fmaxf(z1, z2));
        zloF = zminV - 0.0102f * gradZ - mgc - 2e-5f;
        const bool elig = (zminV - mgc - 2e-5f) > 0.0f;
        zhiF = elig ? (zmaxV + mgc + 2e-5f) : -1.0f;
    }
    ga[idx]     = make_float4(Zx, Zy, Zc, mgc);
    cc[3*idx+0] = make_float4(n0x, n0y, n0c, n1x);
    cc[3*idx+1] = make_float4(n1y, n1c, n2x, n2y);
    cc[3*idx+2] = make_float4(n2c, zloF, zhiF, 0.0f);
    hh[3*idx+0] = make_float4(v0x, v0y, v1x, v1y);
    hh[3*idx+1] = make_float4(v2x, v2y, z0, z1);
    hh[3*idx+2] = make_float4(z2, area_safe, 0.0f, 0.0f);
}

// Heavy path: exact numpy-order c's, true divisions, exact z, exact validity. (R8-proven)
__device__ __forceinline__ void heavy_face(float4 h0, float4 h1, float4 h2,
                                           int fidx, bool pass, float px, float py,
                                           float tz[KTOP], float ts[KTOP],
                                           float& bestZ, int& bestIdx)
{
    if (!pass) return;
    const float v0x=h0.x, v0y=h0.y, v1x=h0.z, v1y=h0.w;
    const float v2x=h1.x, v2y=h1.y, z0=h1.z, z1=h1.w;
    const float z2=h2.x, area=h2.y;
    const float e01x = __fsub_rn(v1x, v0x), e01y = __fsub_rn(v1y, v0y);
    const float e12x = __fsub_rn(v2x, v1x), e12y = __fsub_rn(v2y, v1y);
    const float e20x = __fsub_rn(v0x, v2x), e20y = __fsub_rn(v0y, v2y);

    const float c0 = __fsub_rn(__fmul_rn(e12x, __fsub_rn(py, v1y)),
                               __fmul_rn(e12y, __fsub_rn(px, v1x)));
    const float c1 = __fsub_rn(__fmul_rn(e20x, __fsub_rn(py, v2y)),
                               __fmul_rn(e20y, __fsub_rn(px, v2x)));
    const float c2 = __fsub_rn(__fmul_rn(e01x, __fsub_rn(py, v0y)),
                               __fmul_rn(e01y, __fsub_rn(px, v0x)));

    const float L01 = fmaxf(__fadd_rn(__fmul_rn(e01x,e01x), __fmul_rn(e01y,e01y)), 1e-12f);
    const float L12 = fmaxf(__fadd_rn(__fmul_rn(e12x,e12x), __fmul_rn(e12y,e12y)), 1e-12f);
    const float L20 = fmaxf(__fadd_rn(__fmul_rn(e20x,e20x), __fmul_rn(e20y,e20y)), 1e-12f);

    const bool ap = area > 0.0f;
    const bool s0 = ap ? (c0 > 0.0f) : (c0 < 0.0f);
    const bool s1 = ap ? (c1 > 0.0f) : (c1 < 0.0f);
    const bool s2 = ap ? (c2 > 0.0f) : (c2 < 0.0f);
    if (!(s0 & s1 & s2)) {
        bool cull = false;
        if (!s0) cull |= (c0 * c0 > BLUR * 1.0002f * L12);
        if (!s1) cull |= (c1 * c1 > BLUR * 1.0002f * L20);
        if (!s2) cull |= (c2 * c2 > BLUR * 1.0002f * L01);
        if (cull) return;
    }

    const float w0 = __fdiv_rn(c0, area);
    const float w1 = __fdiv_rn(c1, area);
    const float w2 = __fdiv_rn(c2, area);
    const float z = __fadd_rn(__fadd_rn(__fmul_rn(w0, z0), __fmul_rn(w1, z1)),
                              __fmul_rn(w2, z2));
    if (!(z > 0.0f)) return;
    if (!(z < tz[KTOP-1])) return;

    const bool inside = (w0 > 0.0f) & (w1 > 0.0f) & (w2 > 0.0f);
    float sd;
    if (inside) {
        const bool sat = (c0*c0 >= 1.0002e-3f * L12) &
                         (c1*c1 >= 1.0002e-3f * L20) &
                         (c2*c2 >= 1.0002e-3f * L01);
        if (sat) {
            sd = -1.0f;
        } else {
            const float d2 = fminf(fminf(
                seg_d2_exact(v0x, v0y, e01x, e01y, L01, px, py),
                seg_d2_exact(v1x, v1y, e12x, e12y, L12, px, py)),
                seg_d2_exact(v2x, v2y, e20x, e20y, L20, px, py));
            sd = -d2;
        }
    } else {
        const float d2 = fminf(fminf(
            seg_d2_exact(v0x, v0y, e01x, e01y, L01, px, py),
            seg_d2_exact(v1x, v1y, e12x, e12y, L12, px, py)),
            seg_d2_exact(v2x, v2y, e20x, e20y, L20, px, py));
        if (!(d2 <= BLUR)) return;
        sd = d2;
    }

    if (z < bestZ) { bestZ = z; bestIdx = fidx; }

    float cz = z, cs = sd;
#pragma unroll
    for (int j = 0; j < KTOP; ++j) {
        if (cz < tz[j]) {
            const float oz = tz[j], os = ts[j];
            tz[j] = cz; ts[j] = cs; cz = oz; cs = os;
        }
    }
}

__global__ __launch_bounds__(64 * NW) void raster_kernel(const float4* __restrict__ gaG,
                                                         const float4* __restrict__ hhG,
                                                         const float4* __restrict__ ccG,
                                                         const int* __restrict__ faces,
                                                         float* __restrict__ out)
{
    const int b = blockIdx.z;
    const int lane = threadIdx.x & 63;
    const int w = __builtin_amdgcn_readfirstlane((int)(threadIdx.x >> 6));
    // tile swizzle (R11): permute tile id to mix dense/sparse tiles across dispatch
    const int lid = blockIdx.y * 28 + blockIdx.x;
    const int pid = (lid * 337) % 784;            // gcd(337,784)=1: a permutation
    const int tx = pid % 28, ty = pid / 28;
    const int x = (tx << 3) + (lane & 7);
    const int y = (ty << 3) + (lane >> 3);
    const float px = __fsub_rn(1.0f, __fdiv_rn(__fadd_rn(__fmul_rn(2.0f, (float)x), 1.0f), (float)SDIM));
    const float py = __fsub_rn(1.0f, __fdiv_rn(__fadd_rn(__fmul_rn(2.0f, (float)y), 1.0f), (float)SDIM));
    const float pcx = __fsub_rn(1.0f, __fdiv_rn((float)(16 * tx + 8), 224.0f));
    const float pcy = __fsub_rn(1.0f, __fdiv_rn((float)(16 * ty + 8), 224.0f));

    // LDS ~38.2 KB -> 4 blocks/CU (R17-proven). sS fp16 (alpha-only), sBI short.
    __shared__ int    sList[CAP];
    __shared__ int    sHist[64];
    __shared__ int    sCnt[NW];
    __shared__ int    sOff[NW];
    __shared__ int    sLen;
    __shared__ float  sT;
    __shared__ float  sZ[NW][64][11];
    __shared__ __half sS[NW][64][KTOP];
    __shared__ short  sBI[NW][64];

    if (threadIdx.x < 64) sHist[threadIdx.x] = 0;
    __syncthreads();

    const float4* __restrict__ ga = gaG + (size_t)b * NF;
    const float4* __restrict__ hh = hhG + (size_t)b * NF * 3;
    const float4* __restrict__ cc = ccG + (size_t)b * NF * 3;

    // ---- Phase 1a: tile-level bounds + histogram of certain-cover z-upper-bounds ----
    const int f0 = w * SEG, f1 = f0 + SEG;
    float dm[10], zl[10];
#pragma unroll
    for (int it = 0; it < 10; ++it) {
        const int f = f0 + it * 64 + lane;
        dm[it] = -3e38f; zl[it] = 3e38f;
        if (f < f1) {
            const float4 a0 = ga[f];
            const float4 cA = cc[3*f+0];
            const float4 cB = cc[3*f+1];
            const float4 cC = cc[3*f+2];
            const float d0 = fmaf(cA.x, pcx, fmaf(cA.y, pcy, cA.z));
            const float d1 = fmaf(cA.w, pcx, fmaf(cB.x, pcy, cB.y));
            const float d2 = fmaf(cB.z, pcx, fmaf(cB.w, pcy, cC.x));
            const float dmin = fminf(d0, fminf(d1, d2));
            const float ztc = fmaf(a0.x, pcx, fmaf(a0.y, pcy, a0.z));
            const float spread = fmaf(fabsf(a0.x), HT, fmaf(fabsf(a0.y), HT, 2.0f * fabsf(a0.w))) + 1e-6f;
            dm[it] = dmin;
            zl[it] = fmaxf(ztc - spread, cC.y);
            if ((cC.z > 0.0f) && (dmin >= COV_THR)) {
                const float zh = fminf(ztc + spread, cC.z);
                int bk = (int)floorf((zh - 0.4f) * 53.333332f);
                bk = max(0, min(63, bk));
                atomicAdd(&sHist[bk], 1);
            }
        }
    }
    __syncthreads();

    // ---- Phase 1b: T_tile = conservative upper bound on every pixel's 10th-z ----
    if (threadIdx.x == 0) {
        int cum = 0; float T = 3e38f;
        for (int k2 = 0; k2 < 64; ++k2) {
            cum += sHist[k2];
            if (cum >= KTOP) { T = (k2 >= 63) ? 3e38f : (0.4f + (float)(k2+1) * 0.01875f + 1e-4f); break; }
        }
        sT = T;
    }
    __syncthreads();
    const float Tt = sT;

    // ---- Phase 1c: count survivors per wave ----
    int svMask = 0, cnt1 = 0;
#pragma unroll
    for (int it = 0; it < 10; ++it) {
        const bool sv = (dm[it] >= REL_THR) && (zl[it] <= Tt);
        if (sv) svMask |= (1 << it);
        cnt1 += (int)__popcll(__ballot(sv));
    }
    if (lane == 0) sCnt[w] = cnt1;
    __syncthreads();
    if (threadIdx.x == 0) {
        int acc = 0;
        for (int w2 = 0; w2 < NW; ++w2) { sOff[w2] = acc; acc += sCnt[w2]; }
        sLen = (acc <= CAP) ? acc : -1;
    }
    __syncthreads();
    const int Ltot = sLen;

    // ---- Phase 1d: emit survivor list in ascending face order ----
    if (Ltot >= 0) {
        const unsigned long long below = ((lane == 63) ? ~0ull : ((1ull << (lane + 1)) - 1ull)) >> 1;
        int woff = sOff[w];
#pragma unroll
        for (int it = 0; it < 10; ++it) {
            const bool sv = (svMask >> it) & 1;
            const unsigned long long m = __ballot(sv);
            if (sv) sList[woff + (int)__popcll(m & below)] = f0 + it * 64 + lane;
            woff += (int)__popcll(m);
        }
    }
    __syncthreads();

    // ---- Phase 2: exact per-pixel scan over survivors, 2x unrolled ----
    // Manual 2-wide unroll overlaps two serial load chains (sList -> ga/cc -> gate);
    // processing order stays A-then-B ascending: ordering semantics bit-identical.
    float tz[KTOP], ts[KTOP];
#pragma unroll
    for (int j = 0; j < KTOP; ++j) { tz[j] = 3e38f; ts[j] = 3e38f; }
    float bestZ = 3e38f;
    int bestIdx = -1;

    if (Ltot >= 0) {
        const int chunk = (Ltot + NW - 1) / NW;
        const int jb = w * chunk, je = min(Ltot, jb + chunk);
        int j = jb;
        for (; j + 1 < je; j += 2) {
            const int fA = __builtin_amdgcn_readfirstlane(sList[j]);
            const int fB = __builtin_amdgcn_readfirstlane(sList[j + 1]);
            const float4 gA = ga[fA];
            const float4 gB = ga[fB];
            const float4 cA0 = cc[3*fA+0], cA1 = cc[3*fA+1], cA2 = cc[3*fA+2];
            const float4 cB0 = cc[3*fB+0], cB1 = cc[3*fB+1], cB2 = cc[3*fB+2];

            // gate A
            {
                const float zt = fmaf(gA.x, px, fmaf(gA.y, py, gA.z));
                const float d0 = fmaf(cA0.x, px, fmaf(cA0.y, py, cA0.z));
                const float d1 = fmaf(cA0.w, px, fmaf(cA1.x, py, cA1.y));
                const float d2 = fmaf(cA1.z, px, fmaf(cA1.w, py, cA2.x));
                const float dmin = fminf(d0, fminf(d1, d2));
                const float thr = fminf(tz[KTOP-1], Tt);
                const bool pass = (zt > -gA.w) & (zt < thr + gA.w) & (dmin >= -0.0102f);
                if (__any(pass)) {
                    heavy_face(hh[3*fA+0], hh[3*fA+1], hh[3*fA+2], fA, pass, px, py,
                               tz, ts, bestZ, bestIdx);
                }
            }
            // gate B (after A: ascending order preserved)
            {
                const float zt = fmaf(gB.x, px, fmaf(gB.y, py, gB.z));
                const float d0 = fmaf(cB0.x, px, fmaf(cB0.y, py, cB0.z));
                const float d1 = fmaf(cB0.w, px, fmaf(cB1.x, py, cB1.y));
                const float d2 = fmaf(cB1.z, px, fmaf(cB1.w, py, cB2.x));
                const float dmin = fminf(d0, fminf(d1, d2));
                const float thr = fminf(tz[KTOP-1], Tt);
                const bool pass = (zt > -gB.w) & (zt < thr + gB.w) & (dmin >= -0.0102f);
                if (__any(pass)) {
                    heavy_face(hh[3*fB+0], hh[3*fB+1], hh[3*fB+2], fB, pass, px, py,
                               tz, ts, bestZ, bestIdx);
                }
            }
        }
        if (j < je) {   // odd tail
            const int f = __builtin_amdgcn_readfirstlane(sList[j]);
            const float4 g = ga[f];
            const float4 cA = cc[3*f+0];
            const float4 cB = cc[3*f+1];
            const float4 cC = cc[3*f+2];
            const float zt  = fmaf(g.x, px, fmaf(g.y, py, g.z));
            const float d0 = fmaf(cA.x, px, fmaf(cA.y, py, cA.z));
            const float d1 = fmaf(cA.w, px, fmaf(cB.x, py, cB.y));
            const float d2 = fmaf(cB.z, px, fmaf(cB.w, py, cC.x));
            const float dmin = fminf(d0, fminf(d1, d2));
            const float thr = fminf(tz[KTOP-1], Tt);
            const bool pass = (zt > -g.w) & (zt < thr + g.w) & (dmin >= -0.0102f);
            if (__any(pass)) {
                heavy_face(hh[3*f+0], hh[3*f+1], hh[3*f+2], f, pass, px, py,
                           tz, ts, bestZ, bestIdx);
            }
        }
    } else {
        // survivor-list overflow: full segment scan, Tt- and dmin-gated
        for (int f = f0; f < f1; ++f) {
            const float4 g = ga[f];
            const float4 cA = cc[3*f+0];
            const float4 cB = cc[3*f+1];
            const float4 cC = cc[3*f+2];
            const float zt  = fmaf(g.x, px, fmaf(g.y, py, g.z));
            const float d0 = fmaf(cA.x, px, fmaf(cA.y, py, cA.z));
            const float d1 = fmaf(cA.w, px, fmaf(cB.x, py, cB.y));
            const float d2 = fmaf(cB.z, px, fmaf(cB.w, py, cC.x));
            const float dmin = fminf(d0, fminf(d1, d2));
            const float thr = fminf(tz[KTOP-1], Tt);
            const bool pass = (zt > -g.w) & (zt < thr + g.w) & (dmin >= -0.0102f);
            if (__any(pass)) {
                heavy_face(hh[3*f+0], hh[3*f+1], hh[3*f+2], f, pass, px, py,
                           tz, ts, bestZ, bestIdx);
            }
        }
    }

    // ---- merge NW per-wave sorted top-K lists per pixel via LDS (R8-proven order) ----
#pragma unroll
    for (int j = 0; j < KTOP; ++j) {
        sZ[w][lane][j] = tz[j];
        sS[w][lane][j] = __float2half(ts[j]);   // fp16: alpha-only (R10/R17-measured 4e-3)
    }
    sZ[w][lane][KTOP] = 3e38f;                  // sentinel: exhausted-list z reads
    sBI[w][lane] = (short)bestIdx;
    __syncthreads();

    if (threadIdx.x < 64) {
        const int p = threadIdx.x;
        float bz = sZ[0][p][0]; int bi = (int)sBI[0][p];
#pragma unroll
        for (int w2 = 1; w2 < NW; ++w2) {
            const float zc = sZ[w2][p][0];
            if (zc < bz) { bz = zc; bi = (int)sBI[w2][p]; }
        }
        int ptr[NW];
#pragma unroll
        for (int w2 = 0; w2 < NW; ++w2) ptr[w2] = 0;
        float prod = 1.0f;
#pragma unroll
        for (int k = 0; k < KTOP; ++k) {
            float mz = 3e38f; int mw = -1;
#pragma unroll
            for (int w2 = 0; w2 < NW; ++w2) {
                const float zc = sZ[w2][p][ptr[w2]];
                if (zc < mz) { mz = zc; mw = w2; }   // strict <: sentinel/empty never wins
            }
            float sd = 3e38f;
#pragma unroll
            for (int w2 = 0; w2 < NW; ++w2) {
                if (w2 == mw) { sd = __half2float(sS[w2][p][ptr[w2]]); ptr[w2]++; }
            }
            prod *= 1.0f / (1.0f + __expf(-sd * 1e4f));   // no selection: factor = 1
        }
        const float alpha = 1.0f - prod;
        const int gx = (tx << 3) + (p & 7);
        const int gy = (ty << 3) + (p >> 3);
        out[(size_t)b * (SDIM * SDIM) + gy * SDIM + gx] = alpha;

        if (bi >= 0) {
            const int* fp = faces + ((size_t)b * NF + bi) * 3;
            float* vis = out + IMG_SZ;
            vis[b * NV + fp[0]] = 1.0f;
            vis[b * NV + fp[1]] = 1.0f;
            vis[b * NV + fp[2]] = 1.0f;
        }
    }
}

extern "C" void kernel_launch(void* const* d_in, const int* in_sizes, int n_in,
                              void* d_out, int out_size, void* d_ws, size_t ws_size,
                              hipStream_t stream)
{
    const float* verts = (const float*)d_in[0];
    const int*   faces = (const int*)d_in[1];
    float* out = (float*)d_out;
    float4* ga = (float4*)d_ws;                                      // 160,000 B
    float4* hh = (float4*)((char*)d_ws + NB * NF * 16);              // 480,000 B
    float4* cc = (float4*)((char*)d_ws + NB * NF * (16 + 48));       // 480,000 B

    const int total = NB * NV;   // 10046 >= NB*NF
    preprocess_kernel<<<dim3((total + 63) / 64), dim3(64), 0, stream>>>(verts, faces, ga, hh, cc, out);
    raster_kernel<<<dim3(SDIM / 8, SDIM / 8, NB), dim3(64 * NW), 0, stream>>>(ga, hh, cc, faces, out);
}

// Round 20
// 179.879 us; speedup vs baseline: 1.0177x; 1.0177x over previous
//
#include <hip/hip_runtime.h>
#include <hip/hip_fp16.h>
#include <math.h>

#define SDIM 224
#define KTOP 10
#define NB 2
#define NV 5023
#define NF 5000
#define BLUR 1e-4f
#define IMG_SZ (NB * SDIM * SDIM)   // 100352
#define NW 8             // waves per block
#define SEG (NF / NW)    // 625
#define CAP 1024         // LDS survivor-list capacity
#define HT 0.031251f     // tile half-extent (7/224) + float slop
#define COV_THR 0.04422f // halfdiag(0.044194)+eps: certain whole-tile cover
#define REL_THR (-0.0543f) // -(halfdiag + 0.01 blur reach + eps)

// Exact (numpy-op-order) point-segment distance^2, matching _edge_d2.
__device__ __forceinline__ float seg_d2_exact(float ax, float ay, float abx, float aby,
                                              float L, float px, float py) {
    float apx = __fsub_rn(px, ax), apy = __fsub_rn(py, ay);
    float dot = __fadd_rn(__fmul_rn(apx, abx), __fmul_rn(apy, aby));
    float t = __fdiv_rn(dot, L);
    t = fminf(fmaxf(t, 0.0f), 1.0f);
    float prx = __fadd_rn(ax, __fmul_rn(t, abx));
    float pry = __fadd_rn(ay, __fmul_rn(t, aby));
    float dx = __fsub_rn(px, prx), dy = __fsub_rn(py, pry);
    return __fadd_rn(__fmul_rn(dx, dx), __fmul_rn(dy, dy));
}

// ga[f]    = {Zx, Zy, Zc, mgc}; hh[3f..] = {v0,v1},{v2,z0,z1},{z2,area} (bit-exact data);
// cc[3f..] = normalized edge lines + z bounds {.., zloF, zhiF, 0}  (conservative gates).
// ALL-FP32 preprocess (R16-proven): gate-only values, margins widened for fp32 error.
__global__ __launch_bounds__(64) void preprocess_kernel(const float* __restrict__ verts,
                                  const int* __restrict__ faces,
                                  float4* __restrict__ ga,
                                  float4* __restrict__ hh,
                                  float4* __restrict__ cc,
                                  float* __restrict__ out)
{
    const int idx = blockIdx.x * blockDim.x + threadIdx.x;
    if (idx < NB * NV) out[IMG_SZ + idx] = 0.0f;     // zero visibility region
    if (idx >= NB * NF) return;
    const int b = idx / NF;
    const int* fp = faces + (size_t)idx * 3;
    const int i0 = fp[0], i1 = fp[1], i2 = fp[2];
    const float* vb = verts + (size_t)b * NV * 3;
    const float v0x = -vb[i0*3+0], v0y = -vb[i0*3+1], z0 = vb[i0*3+2];
    const float v1x = -vb[i1*3+0], v1y = -vb[i1*3+1], z1 = vb[i1*3+2];
    const float v2x = -vb[i2*3+0], v2y = -vb[i2*3+1], z2 = vb[i2*3+2];
    const float e01x = __fsub_rn(v1x, v0x), e01y = __fsub_rn(v1y, v0y);
    const float e12x = __fsub_rn(v2x, v1x), e12y = __fsub_rn(v2y, v1y);
    const float e20x = __fsub_rn(v0x, v2x), e20y = __fsub_rn(v0y, v2y);
    const float area = __fsub_rn(__fmul_rn(e01x, __fsub_rn(v2y, v0y)),
                                 __fmul_rn(e01y, __fsub_rn(v2x, v0x)));
    const bool good = fabsf(area) > 1e-10f;
    const float area_safe = good ? area : 1.0f;

    float Zx = 0.0f, Zy = 0.0f, Zc = 0.0f;
    float mgc = -1.0f;   // mgc<0 => zt window always fails
    float n0x=0,n0y=0,n0c=-3e38f, n1x=0,n1y=0,n1c=-3e38f, n2x=0,n2y=0,n2c=-3e38f;
    float zloF = 3e38f, zhiF = -1.0f;
    if (good) {
        const float invA = 1.0f / area;
        const float c0c = e12y*v1x - e12x*v1y;
        const float c1c = e20y*v2x - e20x*v2y;
        const float c2c = e01y*v0x - e01x*v0y;
        Zx = (-e12y*z0 - e20y*z1 - e01y*z2) * invA;
        Zy = ( e12x*z0 + e20x*z1 + e01x*z2) * invA;
        Zc = (c0c*z0 + c1c*z1 + c2c*z2) * invA;
        const float B0 = fabsf(e12x)*(1.0f+fabsf(v1y)) + fabsf(e12y)*(1.0f+fabsf(v1x));
        const float B1 = fabsf(e20x)*(1.0f+fabsf(v2y)) + fabsf(e20y)*(1.0f+fabsf(v2x));
        const float B2 = fabsf(e01x)*(1.0f+fabsf(v0y)) + fabsf(e01y)*(1.0f+fabsf(v0x));
        const float B = (B0*z0 + B1*z1 + B2*z2) * fabsf(invA);
        mgc = 8e-6f * B + 1e-7f;   // >=4x headroom over worst-case fp32 error
        const float s = (area > 0.0f) ? 1.0f : -1.0f;
        const float l12 = sqrtf(e12x*e12x + e12y*e12y);
        const float l20 = sqrtf(e20x*e20x + e20y*e20y);
        const float l01 = sqrtf(e01x*e01x + e01y*e01y);
        const float i12 = s / fmaxf(l12, 1e-30f);
        const float i20 = s / fmaxf(l20, 1e-30f);
        const float i01 = s / fmaxf(l01, 1e-30f);
        n0x = -e12y * i12;
        n0y =  e12x * i12;
        n0c = (e12y*v1x - e12x*v1y) * i12;
        n1x = -e20y * i20;
        n1y =  e20x * i20;
        n1c = (e20y*v2x - e20x*v2y) * i20;
        n2x = -e01y * i01;
        n2y =  e01x * i01;
        n2c = (e01y*v0x - e01x*v0y) * i01;
        const float gradZ = sqrtf(Zx*Zx + Zy*Zy);
        const float zminV = fminf(z0, fminf(z1, z2));
        const float zmaxV = fmaxf(z0, fmaxf(z1, z2));
        zloF = zminV - 0.0102f * gradZ - mgc - 2e-5f;
        const bool elig = (zminV - mgc - 2e-5f) > 0.0f;
        zhiF = elig ? (zmaxV + mgc + 2e-5f) : -1.0f;
    }
    ga[idx]     = make_float4(Zx, Zy, Zc, mgc);
    cc[3*idx+0] = make_float4(n0x, n0y, n0c, n1x);
    cc[3*idx+1] = make_float4(n1y, n1c, n2x, n2y);
    cc[3*idx+2] = make_float4(n2c, zloF, zhiF, 0.0f);
    hh[3*idx+0] = make_float4(v0x, v0y, v1x, v1y);
    hh[3*idx+1] = make_float4(v2x, v2y, z0, z1);
    hh[3*idx+2] = make_float4(z2, area_safe, 0.0f, 0.0f);
}

// Heavy path: exact numpy-order c's, true divisions, exact z, exact validity. (R8-proven)
__device__ __forceinline__ void heavy_face(float4 h0, float4 h1, float4 h2,
                                           int fidx, bool pass, float px, float py,
                                           float tz[KTOP], float ts[KTOP],
                                           float& bestZ, int& bestIdx)
{
    if (!pass) return;
    const float v0x=h0.x, v0y=h0.y, v1x=h0.z, v1y=h0.w;
    const float v2x=h1.x, v2y=h1.y, z0=h1.z, z1=h1.w;
    const float z2=h2.x, area=h2.y;
    const float e01x = __fsub_rn(v1x, v0x), e01y = __fsub_rn(v1y, v0y);
    const float e12x = __fsub_rn(v2x, v1x), e12y = __fsub_rn(v2y, v1y);
    const float e20x = __fsub_rn(v0x, v2x), e20y = __fsub_rn(v0y, v2y);

    const float c0 = __fsub_rn(__fmul_rn(e12x, __fsub_rn(py, v1y)),
                               __fmul_rn(e12y, __fsub_rn(px, v1x)));
    const float c1 = __fsub_rn(__fmul_rn(e20x, __fsub_rn(py, v2y)),
                               __fmul_rn(e20y, __fsub_rn(px, v2x)));
    const float c2 = __fsub_rn(__fmul_rn(e01x, __fsub_rn(py, v0y)),
                               __fmul_rn(e01y, __fsub_rn(px, v0x)));

    const float L01 = fmaxf(__fadd_rn(__fmul_rn(e01x,e01x), __fmul_rn(e01y,e01y)), 1e-12f);
    const float L12 = fmaxf(__fadd_rn(__fmul_rn(e12x,e12x), __fmul_rn(e12y,e12y)), 1e-12f);
    const float L20 = fmaxf(__fadd_rn(__fmul_rn(e20x,e20x), __fmul_rn(e20y,e20y)), 1e-12f);

    const bool ap = area > 0.0f;
    const bool s0 = ap ? (c0 > 0.0f) : (c0 < 0.0f);
    const bool s1 = ap ? (c1 > 0.0f) : (c1 < 0.0f);
    const bool s2 = ap ? (c2 > 0.0f) : (c2 < 0.0f);
    if (!(s0 & s1 & s2)) {
        bool cull = false;
        if (!s0) cull |= (c0 * c0 > BLUR * 1.0002f * L12);
        if (!s1) cull |= (c1 * c1 > BLUR * 1.0002f * L20);
        if (!s2) cull |= (c2 * c2 > BLUR * 1.0002f * L01);
        if (cull) return;
    }

    const float w0 = __fdiv_rn(c0, area);
    const float w1 = __fdiv_rn(c1, area);
    const float w2 = __fdiv_rn(c2, area);
    const float z = __fadd_rn(__fadd_rn(__fmul_rn(w0, z0), __fmul_rn(w1, z1)),
                              __fmul_rn(w2, z2));
    if (!(z > 0.0f)) return;
    if (!(z < tz[KTOP-1])) return;

    const bool inside = (w0 > 0.0f) & (w1 > 0.0f) & (w2 > 0.0f);
    float sd;
    if (inside) {
        const bool sat = (c0*c0 >= 1.0002e-3f * L12) &
                         (c1*c1 >= 1.0002e-3f * L20) &
                         (c2*c2 >= 1.0002e-3f * L01);
        if (sat) {
            sd = -1.0f;
        } else {
            const float d2 = fminf(fminf(
                seg_d2_exact(v0x, v0y, e01x, e01y, L01, px, py),
                seg_d2_exact(v1x, v1y, e12x, e12y, L12, px, py)),
                seg_d2_exact(v2x, v2y, e20x, e20y, L20, px, py));
            sd = -d2;
        }
    } else {
        const float d2 = fminf(fminf(
            seg_d2_exact(v0x, v0y, e01x, e01y, L01, px, py),
            seg_d2_exact(v1x, v1y, e12x, e12y, L12, px, py)),
            seg_d2_exact(v2x, v2y, e20x, e20y, L20, px, py));
        if (!(d2 <= BLUR)) return;
        sd = d2;
    }

    if (z < bestZ) { bestZ = z; bestIdx = fidx; }

    float cz = z, cs = sd;
#pragma unroll
    for (int j = 0; j < KTOP; ++j) {
        if (cz < tz[j]) {
            const float oz = tz[j], os = ts[j];
            tz[j] = cz; ts[j] = cs; cz = oz; cs = os;
        }
    }
}

__global__ __launch_bounds__(64 * NW) void raster_kernel(const float4* __restrict__ gaG,
                                                         const float4* __restrict__ hhG,
                                                         const float4* __restrict__ ccG,
                                                         const int* __restrict__ faces,
                                                         float* __restrict__ out)
{
    const int b = blockIdx.z;
    const int lane = threadIdx.x & 63;
    const int w = __builtin_amdgcn_readfirstlane((int)(threadIdx.x >> 6));
    // tile swizzle (R11): permute tile id to mix dense/sparse tiles across dispatch
    const int lid = blockIdx.y * 28 + blockIdx.x;
    const int pid = (lid * 337) % 784;            // gcd(337,784)=1: a permutation
    const int tx = pid % 28, ty = pid / 28;
    const int x = (tx << 3) + (lane & 7);
    const int y = (ty << 3) + (lane >> 3);
    const float px = __fsub_rn(1.0f, __fdiv_rn(__fadd_rn(__fmul_rn(2.0f, (float)x), 1.0f), (float)SDIM));
    const float py = __fsub_rn(1.0f, __fdiv_rn(__fadd_rn(__fmul_rn(2.0f, (float)y), 1.0f), (float)SDIM));
    const float pcx = __fsub_rn(1.0f, __fdiv_rn((float)(16 * tx + 8), 224.0f));
    const float pcy = __fsub_rn(1.0f, __fdiv_rn((float)(16 * ty + 8), 224.0f));

    // LDS ~38.2 KB -> 4 blocks/CU (R17-proven). sS fp16 (alpha-only), sBI short.
    __shared__ int    sList[CAP];
    __shared__ int    sHist[64];
    __shared__ int    sCnt[NW];
    __shared__ int    sOff[NW];
    __shared__ int    sLen;
    __shared__ float  sT;
    __shared__ float  sZ[NW][64][11];
    __shared__ __half sS[NW][64][KTOP];
    __shared__ short  sBI[NW][64];

    if (threadIdx.x < 64) sHist[threadIdx.x] = 0;
    __syncthreads();

    const float4* __restrict__ ga = gaG + (size_t)b * NF;
    const float4* __restrict__ hh = hhG + (size_t)b * NF * 3;
    const float4* __restrict__ cc = ccG + (size_t)b * NF * 3;

    // ---- Phase 1a: tile-level bounds + histogram of certain-cover z-upper-bounds ----
    const int f0 = w * SEG, f1 = f0 + SEG;
    float dm[10], zl[10];
#pragma unroll
    for (int it = 0; it < 10; ++it) {
        const int f = f0 + it * 64 + lane;
        dm[it] = -3e38f; zl[it] = 3e38f;
        if (f < f1) {
            const float4 a0 = ga[f];
            const float4 cA = cc[3*f+0];
            const float4 cB = cc[3*f+1];
            const float4 cC = cc[3*f+2];
            const float d0 = fmaf(cA.x, pcx, fmaf(cA.y, pcy, cA.z));
            const float d1 = fmaf(cA.w, pcx, fmaf(cB.x, pcy, cB.y));
            const float d2 = fmaf(cB.z, pcx, fmaf(cB.w, pcy, cC.x));
            const float dmin = fminf(d0, fminf(d1, d2));
            const float ztc = fmaf(a0.x, pcx, fmaf(a0.y, pcy, a0.z));
            const float spread = fmaf(fabsf(a0.x), HT, fmaf(fabsf(a0.y), HT, 2.0f * fabsf(a0.w))) + 1e-6f;
            dm[it] = dmin;
            zl[it] = fmaxf(ztc - spread, cC.y);
            if ((cC.z > 0.0f) && (dmin >= COV_THR)) {
                const float zh = fminf(ztc + spread, cC.z);
                int bk = (int)floorf((zh - 0.4f) * 53.333332f);
                bk = max(0, min(63, bk));
                atomicAdd(&sHist[bk], 1);
            }
        }
    }
    __syncthreads();

    // ---- Phase 1b: T_tile = conservative upper bound on every pixel's 10th-z ----
    if (threadIdx.x == 0) {
        int cum = 0; float T = 3e38f;
        for (int k2 = 0; k2 < 64; ++k2) {
            cum += sHist[k2];
            if (cum >= KTOP) { T = (k2 >= 63) ? 3e38f : (0.4f + (float)(k2+1) * 0.01875f + 1e-4f); break; }
        }
        sT = T;
    }
    __syncthreads();
    const float Tt = sT;

    // ---- Phase 1c: count survivors per wave ----
    int svMask = 0, cnt1 = 0;
#pragma unroll
    for (int it = 0; it < 10; ++it) {
        const bool sv = (dm[it] >= REL_THR) && (zl[it] <= Tt);
        if (sv) svMask |= (1 << it);
        cnt1 += (int)__popcll(__ballot(sv));
    }
    if (lane == 0) sCnt[w] = cnt1;
    __syncthreads();
    if (threadIdx.x == 0) {
        int acc = 0;
        for (int w2 = 0; w2 < NW; ++w2) { sOff[w2] = acc; acc += sCnt[w2]; }
        sLen = (acc <= CAP) ? acc : -1;
    }
    __syncthreads();
    const int Ltot = sLen;

    // ---- Phase 1d: emit survivor list in ascending face order ----
    if (Ltot >= 0) {
        const unsigned long long below = ((lane == 63) ? ~0ull : ((1ull << (lane + 1)) - 1ull)) >> 1;
        int woff = sOff[w];
#pragma unroll
        for (int it = 0; it < 10; ++it) {
            const bool sv = (svMask >> it) & 1;
            const unsigned long long m = __ballot(sv);
            if (sv) sList[woff + (int)__popcll(m & below)] = f0 + it * 64 + lane;
            woff += (int)__popcll(m);
        }
    }
    __syncthreads();

    // ---- Phase 2: exact per-pixel scan over survivors (R18-proven best) ----
    float tz[KTOP], ts[KTOP];
#pragma unroll
    for (int j = 0; j < KTOP; ++j) { tz[j] = 3e38f; ts[j] = 3e38f; }
    float bestZ = 3e38f;
    int bestIdx = -1;

    if (Ltot >= 0) {
        const int chunk = (Ltot + NW - 1) / NW;
        const int jb = w * chunk, je = min(Ltot, jb + chunk);
        for (int j = jb; j < je; ++j) {
            const int f = __builtin_amdgcn_readfirstlane(sList[j]);
            const float4 g = ga[f];
            const float4 cA = cc[3*f+0];
            const float4 cB = cc[3*f+1];
            const float4 cC = cc[3*f+2];
            const float zt  = fmaf(g.x, px, fmaf(g.y, py, g.z));
            const float d0 = fmaf(cA.x, px, fmaf(cA.y, py, cA.z));
            const float d1 = fmaf(cA.w, px, fmaf(cB.x, py, cB.y));
            const float d2 = fmaf(cB.z, px, fmaf(cB.w, py, cC.x));
            const float dmin = fminf(d0, fminf(d1, d2));
            const float thr = fminf(tz[KTOP-1], Tt);
            const bool pass = (zt > -g.w) & (zt < thr + g.w) & (dmin >= -0.0102f);
            if (__any(pass)) {
                heavy_face(hh[3*f+0], hh[3*f+1], hh[3*f+2], f, pass, px, py,
                           tz, ts, bestZ, bestIdx);
            }
        }
    } else {
        // survivor-list overflow: full segment scan, Tt- and dmin-gated
        for (int f = f0; f < f1; ++f) {
            const float4 g = ga[f];
            const float4 cA = cc[3*f+0];
            const float4 cB = cc[3*f+1];
            const float4 cC = cc[3*f+2];
            const float zt  = fmaf(g.x, px, fmaf(g.y, py, g.z));
            const float d0 = fmaf(cA.x, px, fmaf(cA.y, py, cA.z));
            const float d1 = fmaf(cA.w, px, fmaf(cB.x, py, cB.y));
            const float d2 = fmaf(cB.z, px, fmaf(cB.w, py, cC.x));
            const float dmin = fminf(d0, fminf(d1, d2));
            const float thr = fminf(tz[KTOP-1], Tt);
            const bool pass = (zt > -g.w) & (zt < thr + g.w) & (dmin >= -0.0102f);
            if (__any(pass)) {
                heavy_face(hh[3*f+0], hh[3*f+1], hh[3*f+2], f, pass, px, py,
                           tz, ts, bestZ, bestIdx);
            }
        }
    }

    // ---- merge NW per-wave sorted top-K lists per pixel via LDS (R8-proven order) ----
#pragma unroll
    for (int j = 0; j < KTOP; ++j) {
        sZ[w][lane][j] = tz[j];
        sS[w][lane][j] = __float2half(ts[j]);   // fp16: alpha-only (R10/R17-measured 4e-3)
    }
    sZ[w][lane][KTOP] = 3e38f;                  // sentinel: exhausted-list z reads
    sBI[w][lane] = (short)bestIdx;
    __syncthreads();

    if (threadIdx.x < 64) {
        const int p = threadIdx.x;
        float bz = sZ[0][p][0]; int bi = (int)sBI[0][p];
#pragma unroll
        for (int w2 = 1; w2 < NW; ++w2) {
            const float zc = sZ[w2][p][0];
            if (zc < bz) { bz = zc; bi = (int)sBI[w2][p]; }
        }
        int ptr[NW];
#pragma unroll
        for (int w2 = 0; w2 < NW; ++w2) ptr[w2] = 0;
        float prod = 1.0f;
#pragma unroll
        for (int k = 0; k < KTOP; ++k) {
            float mz = 3e38f; int mw = -1;
#pragma unroll
            for (int w2 = 0; w2 < NW; ++w2) {
                const float zc = sZ[w2][p][ptr[w2]];
                if (zc < mz) { mz = zc; mw = w2; }   // strict <: sentinel/empty never wins
            }
            float sd = 3e38f;
#pragma unroll
            for (int w2 = 0; w2 < NW; ++w2) {
                if (w2 == mw) { sd = __half2float(sS[w2][p][ptr[w2]]); ptr[w2]++; }
            }
            prod *= 1.0f / (1.0f + __expf(-sd * 1e4f));   // no selection: factor = 1
        }
        const float alpha = 1.0f - prod;
        const int gx = (tx << 3) + (p & 7);
        const int gy = (ty << 3) + (p >> 3);
        out[(size_t)b * (SDIM * SDIM) + gy * SDIM + gx] = alpha;

        if (bi >= 0) {
            const int* fp = faces + ((size_t)b * NF + bi) * 3;
            float* vis = out + IMG_SZ;
            vis[b * NV + fp[0]] = 1.0f;
            vis[b * NV + fp[1]] = 1.0f;
            vis[b * NV + fp[2]] = 1.0f;
        }
    }
}

extern "C" void kernel_launch(void* const* d_in, const int* in_sizes, int n_in,
                              void* d_out, int out_size, void* d_ws, size_t ws_size,
                              hipStream_t stream)
{
    const float* verts = (const float*)d_in[0];
    const int*   faces = (const int*)d_in[1];
    float* out = (float*)d_out;
    float4* ga = (float4*)d_ws;                                      // 160,000 B
    float4* hh = (float4*)((char*)d_ws + NB * NF * 16);              // 480,000 B
    float4* cc = (float4*)((char*)d_ws + NB * NF * (16 + 48));       // 480,000 B

    const int total = NB * NV;   // 10046 >= NB*NF
    preprocess_kernel<<<dim3((total + 63) / 64), dim3(64), 0, stream>>>(verts, faces, ga, hh, cc, out);
    raster_kernel<<<dim3(SDIM / 8, SDIM / 8, NB), dim3(64 * NW), 0, stream>>>(ga, hh, cc, faces, out);
}